// Round 6
// baseline (7947.576 us; speedup 1.0000x reference)
//
#include <hip/hip_runtime.h>
#include <stdint.h>

// Problem constants
#define kS 256      // sequence length
#define kB 256      // batch
#define kE 300      // embedding dim
#define kH 300      // hidden per direction
#define kG 1200     // 4*H gate rows
#define kT 9        // tags

// R5 post-mortem: per-step wall (~29 us) is invariant to wave count, L2
// traffic, and prefetch depth (R0 vs R4 vs R5). The common factor: ONE block
// per CU, all waves lockstepped by ~6 barriers + a cross-XCD h-exchange per
// step -- during barrier/vmcnt drains and the narrow cell/emission phases the
// CU has nothing to issue. R6: TWO independent blocks per CU, mutually out of
// phase, so one block's GEMM covers the other's stalls.
//   TILE_B 4->2, 512 blocks (2 dir x 2 q x 128 tiles), LDS ~67 KB/block ->
//   2 blocks/CU, 20 waves/CU. GEMM bodies are R4's proven 48-VGPR ping-pong
//   form. __launch_bounds__(640,4) caps VGPR at ~64 (cap rule fitted from R1:
//   w=3 -> 84 ~= 512/6; w=4 -> 64) -- never below the body's ~48 need, but
//   guards the 2-block-residency cliff.
#define ROWS 600        // gate rows per block (600 = 150 units x 4 gates)
#define TILE_B 2        // batch rows per block
#define TCHUNK 8        // timesteps per input-projection chunk
#define NTH 640         // threads per block (10 waves)
#define NAX (TCHUNK * TILE_B)     // 16 gathered embedding rows
#define HXN (TILE_B * 150)        // 300 h values exchanged per step
#define SLICE_F4 45000  // 75 * 600 float4 per weight slice
#define EMSZ (kS * kB * kT)
#define NBLK 512

__device__ __forceinline__ float sigmoidf_(float v) { return 1.0f / (1.0f + expf(-v)); }

// -----------------------------------------------------------------------------
// Pre-pass: transpose [1200][300] weights into per-split k-major float4 layout.
// wt[m][q][kc][rr]: consecutive rr (= consecutive tid) read consecutive 16B.
// Also zeroes the 512 exchange flags (must happen every launch).
// -----------------------------------------------------------------------------
__global__ __launch_bounds__(256) void transpose_w_all(
    const float* __restrict__ w_ih_f, const float* __restrict__ w_hh_f,
    const float* __restrict__ w_ih_b, const float* __restrict__ w_hh_b,
    float4* __restrict__ wt, int* __restrict__ flags)
{
    const int m = blockIdx.y;  // 0: ih_f, 1: hh_f, 2: ih_b, 3: hh_b
    const float* w = (m == 0) ? w_ih_f : (m == 1) ? w_hh_f : (m == 2) ? w_ih_b : w_hh_b;
    if (blockIdx.y == 0 && blockIdx.x == 0) {
        flags[threadIdx.x] = 0;
        flags[256 + threadIdx.x] = 0;
    }
    int i = blockIdx.x * 256 + threadIdx.x;
    if (i >= 2 * SLICE_F4) return;
    const int q    = i / SLICE_F4;
    const int rem  = i - q * SLICE_F4;
    const int kc   = rem / ROWS;
    const int rr   = rem - kc * ROWS;
    const int gate = rr / 150;
    const int ii   = rr - gate * 150;
    const int r    = gate * 300 + q * 150 + ii;
    const float* p = w + (size_t)r * 300 + kc * 4;
    wt[(size_t)m * 2 * SLICE_F4 + i] = make_float4(p[0], p[1], p[2], p[3]);
}

// -----------------------------------------------------------------------------
// Fused BiLSTM, split-pair version, 2 blocks/CU.
//  block -> (dir, q, tile): xcd = bi&7: dir=xcd>>2, q=(xcd>>1)&1, so each XCD
//  hosts one (dir,q) combo -> 1.44 MB weight working set per XCD L2.
//  Partner blocks (same dir,tile; q vs 1-q) exchange their 150-unit h slice
//  every step through hxh (parity double-buffered) + monotonic step flags.
//  Exchange uses agent-scope relaxed atomics, no fences (no L2 flush).
// -----------------------------------------------------------------------------
__global__ __launch_bounds__(NTH, 4) void ner_bilstm_kernel(
    const int*    __restrict__ x,
    const float*  __restrict__ emb,
    const float4* __restrict__ wt,       // 4 matrices x 2 slices, k-major
    const float*  __restrict__ bih_f, const float* __restrict__ bhh_f,
    const float*  __restrict__ bih_b, const float* __restrict__ bhh_b,
    const float*  __restrict__ w_proj,   // [9][600]
    float*        __restrict__ em_all,   // 2 dir slabs [S][B][9]
    float*        __restrict__ hxh,      // h exchange: [gid2+q][2][HXN]
    float*        __restrict__ hxa,      // em-partial exchange: [gid2+q][2][40]
    int*          __restrict__ flags)    // [512] step counters
{
    extern __shared__ float s_pre[];                 // [16][600] = 38.4 KB dynamic
    __shared__ float s_Ax[NAX][304];                 // gathered embeddings (19.5 KB)
    __shared__ float s_h[TILE_B][304];               // full h_{t-1} (both halves)
    __shared__ float s_c[TILE_B][152];               // own 150 c values
    __shared__ float s_gbuf[TILE_B][ROWS];           // own gate preacts
    __shared__ float s_emp[TILE_B][kT][10];          // emission partial chunks
    __shared__ float s_emf[40], s_emf2[40];          // reduced partials (q0)
    // total LDS ~67.3 KB -> 2 blocks/CU.

    const int bi   = blockIdx.x;
    const int xcd  = bi & 7;
    const int dir  = xcd >> 2;
    const int q    = (xcd >> 1) & 1;
    const int tile = (bi >> 3) * 2 + (xcd & 1);      // 0..127
    const int tid  = threadIdx.x;

    const float4* wih4 = wt + ((size_t)(dir * 2 + 0)) * 2 * SLICE_F4 + (size_t)q * SLICE_F4;
    const float4* whh4 = wt + ((size_t)(dir * 2 + 1)) * 2 * SLICE_F4 + (size_t)q * SLICE_F4;
    const float*  bih  = dir ? bih_b : bih_f;
    const float*  bhh  = dir ? bhh_b : bhh_f;
    float* emout = em_all + (size_t)dir * EMSZ;

    const int gid2 = (dir * 128 + tile) * 2;
    float* hx_own  = hxh + (size_t)(gid2 + q)       * 2 * HXN;
    float* hx_par  = hxh + (size_t)(gid2 + (1 - q)) * 2 * HXN;
    float* hxa_own = hxa + (size_t)(gid2 + q)       * 2 * 40;
    float* hxa_par = hxa + (size_t)(gid2 + (1 - q)) * 2 * 40;
    int* flag_own  = flags + gid2 + q;
    int* flag_par  = flags + gid2 + (1 - q);

    float bsum = 0.0f;
    if (tid < ROWS) {
        const int gate = tid / 150, ii = tid - gate * 150;
        const int r = gate * 300 + q * 150 + ii;
        bsum = bih[r] + bhh[r];
    }

    for (int i = tid; i < TILE_B * 304; i += NTH) (&s_h[0][0])[i] = 0.0f;
    for (int i = tid; i < TILE_B * 152; i += NTH) (&s_c[0][0])[i] = 0.0f;
    __syncthreads();

    for (int tc = 0; tc < kS / TCHUNK; ++tc) {
        // ---- embedding gather: 16 (tt,b2) rows, 40 lanes each ------------------
        {
            const int rr = tid / 40, ln = tid - rr * 40;
            const int tt = rr >> 1, b2 = rr & 1;
            const int t  = tc * TCHUNK + tt;
            const int s  = dir ? (kS - 1 - t) : t;
            const int token = x[(tile * TILE_B + b2) * kS + s];
            const float* erow = emb + (size_t)token * kE;
            for (int e = ln; e < kE; e += 40) s_Ax[rr][e] = erow[e];
        }
        __syncthreads();

        // ---- input projection: 2 passes of 8 columns (R4's spill-free shape) ---
        if (tid < ROWS) {
#pragma unroll 1
            for (int half = 0; half < 2; ++half) {
                const int ub = half * 8;
                float acc[8];
#pragma unroll
                for (int u = 0; u < 8; ++u) acc[u] = bsum;
                const float4* wl = wih4 + tid;
                float4 wc = *wl; wl += ROWS;
#pragma unroll 1
                for (int kc = 0; kc < 74; ++kc) {
                    const float4 wn = *wl; wl += ROWS;
                    const int k4 = kc * 4;
#pragma unroll
                    for (int u = 0; u < 8; ++u) {
                        const float4 a = *(const float4*)&s_Ax[ub + u][k4];
                        acc[u] += wc.x*a.x + wc.y*a.y + wc.z*a.z + wc.w*a.w;
                    }
                    wc = wn;
                }
#pragma unroll
                for (int u = 0; u < 8; ++u) {
                    const float4 a = *(const float4*)&s_Ax[ub + u][74 * 4];
                    acc[u] += wc.x*a.x + wc.y*a.y + wc.z*a.z + wc.w*a.w;
                }
#pragma unroll
                for (int u = 0; u < 8; ++u) s_pre[(ub + u) * ROWS + tid] = acc[u];
            }
        }
        __syncthreads();

        // ---- recurrent steps ---------------------------------------------------
        for (int tt = 0; tt < TCHUNK; ++tt) {
            const int t   = tc * TCHUNK + tt;
            const int s   = dir ? (kS - 1 - t) : t;
            const int par = t & 1;

            // gates = pre + h_{t-1} @ w_hh_slice^T (1-deep ping-pong, ~48 VGPR)
            if (tid < ROWS) {
                float a0 = s_pre[(tt * 2 + 0) * ROWS + tid];
                float a1 = s_pre[(tt * 2 + 1) * ROWS + tid];
                const float4* wl = whh4 + tid;
                float4 wc = *wl; wl += ROWS;
#pragma unroll 2
                for (int kc = 0; kc < 74; ++kc) {
                    const float4 wn = *wl; wl += ROWS;
                    const int k4 = kc * 4;
                    const float4 h0 = *(const float4*)&s_h[0][k4];
                    const float4 h1 = *(const float4*)&s_h[1][k4];
                    a0 += wc.x*h0.x + wc.y*h0.y + wc.z*h0.z + wc.w*h0.w;
                    a1 += wc.x*h1.x + wc.y*h1.y + wc.z*h1.z + wc.w*h1.w;
                    wc = wn;
                }
                {   // kc = 74 tail
                    const int k4 = 74 * 4;
                    const float4 h0 = *(const float4*)&s_h[0][k4];
                    const float4 h1 = *(const float4*)&s_h[1][k4];
                    a0 += wc.x*h0.x + wc.y*h0.y + wc.z*h0.z + wc.w*h0.w;
                    a1 += wc.x*h1.x + wc.y*h1.y + wc.z*h1.z + wc.w*h1.w;
                }
                s_gbuf[0][tid] = a0; s_gbuf[1][tid] = a1;
            }
            __syncthreads();

            // cell update for own 150 units x 2 batches; store h to exchange buf
            if (tid < HXN) {
                const int b = tid / 150, i2 = tid - b * 150;
                const float gi = s_gbuf[b][i2];
                const float gf = s_gbuf[b][150 + i2];
                const float gg = s_gbuf[b][300 + i2];
                const float go = s_gbuf[b][450 + i2];
                const float c  = sigmoidf_(gf) * s_c[b][i2] + sigmoidf_(gi) * tanhf(gg);
                const float h  = sigmoidf_(go) * tanhf(c);
                s_c[b][i2] = c;
                s_h[b][q * 150 + i2] = h;
                __hip_atomic_store(&hx_own[par * HXN + tid], h,
                                   __ATOMIC_RELAXED, __HIP_MEMORY_SCOPE_AGENT);
            }
            __syncthreads();

            // emission partials over own slice
            if (tid < 180) {
                const int b = tid / 90, rem = tid - b * 90;
                const int tag = rem / 10, ch = rem - tag * 10;
                const int n0 = ch * 15;
                const float* wrow = w_proj + tag * (2 * kH) + dir * kH + q * 150 + n0;
                const float* hrow = &s_h[b][q * 150 + n0];
                float sum = 0.0f;
#pragma unroll
                for (int k2 = 0; k2 < 15; ++k2) sum += hrow[k2] * wrow[k2];
                s_emp[b][tag][ch] = sum;
            }
            __syncthreads();
            if (tid < TILE_B * kT) {
                const int b = tid / kT, tag = tid - b * kT;
                float v = 0.0f;
#pragma unroll
                for (int ch = 0; ch < 10; ++ch) v += s_emp[b][tag][ch];
                if (q) __hip_atomic_store(&hxa_own[par * 40 + tid], v,
                                          __ATOMIC_RELAXED, __HIP_MEMORY_SCOPE_AGENT);
                else   s_emf[tid] = v;
            }
            // each wave drains its own agent stores, barrier, then signal
            asm volatile("s_waitcnt vmcnt(0)" ::: "memory");
            __syncthreads();
            if (tid == 0) {
                __hip_atomic_store(flag_own, t + 1,
                                   __ATOMIC_RELAXED, __HIP_MEMORY_SCOPE_AGENT);
                int spins = 0;
                while (__hip_atomic_load(flag_par, __ATOMIC_RELAXED,
                                         __HIP_MEMORY_SCOPE_AGENT) < t + 1) {
                    __builtin_amdgcn_s_sleep(1);
                    if (++spins > (1 << 22)) break;   // hang safety
                }
            }
            __syncthreads();
            // pull partner's h half (+ partner emission partial for q0)
            if (tid < HXN) {
                const int b = tid / 150, i2 = tid - b * 150;
                s_h[b][(1 - q) * 150 + i2] =
                    __hip_atomic_load(&hx_par[par * HXN + tid],
                                      __ATOMIC_RELAXED, __HIP_MEMORY_SCOPE_AGENT);
            } else if (!q && tid < HXN + TILE_B * kT) {
                s_emf2[tid - HXN] =
                    __hip_atomic_load(&hxa_par[par * 40 + (tid - HXN)],
                                      __ATOMIC_RELAXED, __HIP_MEMORY_SCOPE_AGENT);
            }
            __syncthreads();
            if (!q && tid < TILE_B * kT) {
                const int b = tid / kT, tag = tid - b * kT;
                emout[((size_t)s * kB + tile * TILE_B + b) * kT + tag] =
                    s_emf[tid] + s_emf2[tid];
            }
            // next phase writes s_gbuf/s_Ax/s_pre, all separated from the reads
            // above by >=2 barriers in the next step
        }
    }
}

// -----------------------------------------------------------------------------
// CRF Viterbi decode (unchanged). 9 lanes per batch row.
// -----------------------------------------------------------------------------
__global__ __launch_bounds__(256) void ner_viterbi_kernel(
    const float* __restrict__ em_all,
    const float* __restrict__ b_proj,
    const float* __restrict__ start_t,
    const float* __restrict__ end_t,
    const float* __restrict__ trans,
    int*         __restrict__ out)
{
    const float* em_f = em_all;
    const float* em_b = em_all + EMSZ;

    __shared__ uint8_t bp[kS - 1][28][kT];

    const int tid  = threadIdx.x;
    const int wave = tid >> 6;
    const int lane = tid & 63;
    const int g    = lane / kT;
    const int nx   = lane % kT;
    const bool active = (g < 7);
    const int gg   = wave * 7 + g;
    const int b    = blockIdx.x * 28 + (active ? gg : 0);
    const bool valid = active && (b < kB);
    const int beff = (b < kB) ? b : (kB - 1);
    const int base = g * kT;

    float tcol[kT];
#pragma unroll
    for (int p = 0; p < kT; ++p) tcol[p] = trans[p * kT + nx];
    const float bpj = b_proj[nx];

    float score = start_t[nx]
                + em_f[(size_t)beff * kT + nx]
                + em_b[(size_t)beff * kT + nx]
                + bpj;

    for (int t = 1; t < kS; ++t) {
        const size_t ei = ((size_t)t * kB + beff) * kT + nx;
        const float em = em_f[ei] + em_b[ei] + bpj;
        float best = -3.402823466e38f;
        int bidx = 0;
#pragma unroll
        for (int p = 0; p < kT; ++p) {
            const float sp = __shfl(score, base + p, 64);
            const float cand = sp + tcol[p];
            if (cand > best) { best = cand; bidx = p; }
        }
        if (valid) bp[t - 1][gg][nx] = (uint8_t)bidx;
        score = best + em;
    }

    score += end_t[nx];
    float best = -3.402823466e38f;
    int last = 0;
#pragma unroll
    for (int p = 0; p < kT; ++p) {
        const float sp = __shfl(score, base + p, 64);
        if (sp > best) { best = sp; last = p; }
    }

    __syncthreads();

    if (valid && nx == 0) {
        int cur = last;
        out[beff * kS + (kS - 1)] = cur;
        for (int t = kS - 2; t >= 0; --t) {
            cur = bp[t][gg][cur];
            out[beff * kS + t] = cur;
        }
    }
}

// -----------------------------------------------------------------------------
extern "C" void kernel_launch(void* const* d_in, const int* in_sizes, int n_in,
                              void* d_out, int out_size, void* d_ws, size_t ws_size,
                              hipStream_t stream) {
    const int*   x       = (const int*)  d_in[0];
    const float* emb     = (const float*)d_in[1];
    const float* w_ih_f  = (const float*)d_in[2];
    const float* w_hh_f  = (const float*)d_in[3];
    const float* b_ih_f  = (const float*)d_in[4];
    const float* b_hh_f  = (const float*)d_in[5];
    const float* w_ih_b  = (const float*)d_in[6];
    const float* w_hh_b  = (const float*)d_in[7];
    const float* b_ih_b  = (const float*)d_in[8];
    const float* b_hh_b  = (const float*)d_in[9];
    const float* w_proj  = (const float*)d_in[10];
    const float* b_proj  = (const float*)d_in[11];
    const float* start_t = (const float*)d_in[12];
    const float* end_t   = (const float*)d_in[13];
    const float* trans   = (const float*)d_in[14];

    // workspace: em (4.72 MB) | wt 4x2 slices (5.76 MB) | hxh (1.23 MB) |
    //            hxa (164 KB) | flags (2 KB)  => ~11.9 MB
    float*  em_all = (float*)d_ws;
    float4* wt     = (float4*)((char*)d_ws + (size_t)2 * EMSZ * 4);
    float*  hxh    = (float*)((char*)wt + (size_t)4 * 2 * SLICE_F4 * sizeof(float4));
    float*  hxa    = hxh + (size_t)NBLK * 2 * HXN;
    int*    flags  = (int*)(hxa + (size_t)NBLK * 2 * 40);

    dim3 tgrid((2 * SLICE_F4 + 255) / 256, 4);
    transpose_w_all<<<tgrid, 256, 0, stream>>>(w_ih_f, w_hh_f, w_ih_b, w_hh_b, wt, flags);

    // 512 blocks (2 dirs x 2 q x 128 tiles); 38.4 KB dynamic LDS -> 2 blocks/CU
    ner_bilstm_kernel<<<NBLK, NTH, NAX * ROWS * sizeof(float), stream>>>(
        x, emb, wt, b_ih_f, b_hh_f, b_ih_b, b_hh_b, w_proj,
        em_all, hxh, hxa, flags);

    ner_viterbi_kernel<<<10, 256, 0, stream>>>(
        em_all, b_proj, start_t, end_t, trans, (int*)d_out);
}

// Round 7
// 6430.402 us; speedup vs baseline: 1.2359x; 1.2359x over previous
//
#include <hip/hip_runtime.h>
#include <stdint.h>

// Problem constants
#define kS 256      // sequence length
#define kB 256      // batch
#define kE 300      // embedding dim
#define kH 300      // hidden per direction
#define kG 1200     // 4*H gate rows
#define kT 9        // tags

// R6 post-mortem: per-step wall scales with per-block work and sits 2.6x above
// the L2-BW floor -> the GEMM phases are dependent-load chains (75 kc deep,
// ping-pong depth 1, ~300-400 cyc effective L2 latency each). R5's deeper
// buffers died on the allocator's empirical 84-VGPR hard cap. R7: break the
// chain with k-split + multi-stream ILP designed to ~75 VGPRs:
//   HH: 8 waves = (k-slice s x batch-pair bp); 10 row-group load streams/wave,
//       19-kc chain, partials in LDS (alias s_Ax) + reduce.
//   IH: 10 waves = (2 k-slices x 5 row-blocks); 2 streams + prefetch, 38-kc
//       chain; slice0 -> s_pre (bias folded), slice1 -> s_ihp partial.
// Weights padded rows 600->640, kc 75->77 (zeros) so dummy lanes compute 0.
#define ROWS 600        // real gate rows per block
#define RRP  640        // padded weight-row dim
#define KCP  77         // padded k-chunks (75 real + 2 zero/prefetch)
#define TILE_B 4        // batch rows per group
#define TCHUNK 8        // timesteps per input-projection chunk
#define NTH 640         // threads per block (10 waves)
#define SLICE_F4 (KCP * RRP)    // 49280 float4 per weight slice
#define EMSZ (kS * kB * kT)

__device__ __forceinline__ float sigmoidf_(float v) { return 1.0f / (1.0f + expf(-v)); }

__device__ __forceinline__ float bias_of(int rr, int q,
                                         const float* __restrict__ bih,
                                         const float* __restrict__ bhh) {
    const int gate = rr / 150, ii = rr - gate * 150;
    const int r = gate * 300 + q * 150 + ii;
    return bih[r] + bhh[r];
}

// -----------------------------------------------------------------------------
// Pre-pass: transpose [1200][300] weights into per-split k-major float4 layout,
// padded to KCP kc x RRP rows (zeros beyond kc>=75 or rr>=600).
// wt[m][q][kc][rr]: consecutive rr (= consecutive lanes) read consecutive 16B.
// -----------------------------------------------------------------------------
__global__ __launch_bounds__(256) void transpose_w_all(
    const float* __restrict__ w_ih_f, const float* __restrict__ w_hh_f,
    const float* __restrict__ w_ih_b, const float* __restrict__ w_hh_b,
    float4* __restrict__ wt, int* __restrict__ flags)
{
    const int m = blockIdx.y;  // 0: ih_f, 1: hh_f, 2: ih_b, 3: hh_b
    const float* w = (m == 0) ? w_ih_f : (m == 1) ? w_hh_f : (m == 2) ? w_ih_b : w_hh_b;
    if (blockIdx.y == 0 && blockIdx.x == 0) flags[threadIdx.x] = 0;
    int i = blockIdx.x * 256 + threadIdx.x;
    if (i >= 2 * SLICE_F4) return;
    const int q    = i / SLICE_F4;
    const int rem  = i - q * SLICE_F4;
    const int kc   = rem / RRP;
    const int rr   = rem - kc * RRP;
    if (kc >= 75 || rr >= ROWS) {
        wt[(size_t)m * 2 * SLICE_F4 + i] = make_float4(0.f, 0.f, 0.f, 0.f);
        return;
    }
    const int gate = rr / 150;
    const int ii   = rr - gate * 150;
    const int r    = gate * 300 + q * 150 + ii;
    const float* p = w + (size_t)r * 300 + kc * 4;
    wt[(size_t)m * 2 * SLICE_F4 + i] = make_float4(p[0], p[1], p[2], p[3]);
}

#define FMA4(W, V, A) A = fmaf((W).x,(V).x,fmaf((W).y,(V).y,fmaf((W).z,(V).z,fmaf((W).w,(V).w,(A)))))

// -----------------------------------------------------------------------------
// Fused BiLSTM, split-pair + k-split version.
//  block -> (dir, q, tile): xcd = bi&7: dir=xcd>>2, q=(xcd>>1)&1; each XCD
//  hosts one (dir,q) combo -> weight working set L2-resident per XCD.
//  Partner blocks (q vs 1-q) exchange their 150-unit h slice every step via
//  hxh (parity double-buffered) + monotonic step flags; agent-scope relaxed
//  atomics, no fences. Protocol verbatim from R4 (5x passing).
// -----------------------------------------------------------------------------
__global__ __launch_bounds__(NTH) void ner_bilstm_kernel(
    const int*    __restrict__ x,
    const float*  __restrict__ emb,
    const float4* __restrict__ wt,       // 4 matrices x 2 slices, k-major padded
    const float*  __restrict__ bih_f, const float* __restrict__ bhh_f,
    const float*  __restrict__ bih_b, const float* __restrict__ bhh_b,
    const float*  __restrict__ w_proj,   // [9][600]
    float*        __restrict__ em_all,   // 2 dir slabs [S][B][9]
    float*        __restrict__ hxh,      // h exchange: [gid2+q][2][600]
    float*        __restrict__ hxa,      // em-partial exchange: [gid2+q][2][40]
    int*          __restrict__ flags)    // [256] step counters
{
    extern __shared__ float s_pre[];                 // [32][600] = 76.8 KB dynamic
    __shared__ float s_Ax[32][304];                  // embeddings; HH partials alias
    __shared__ float s_ihp[8][600];                  // IH slice-1 partials (19.2 KB)
    __shared__ float s_h[TILE_B][304];               // full h_{t-1} (pad cols = 0)
    __shared__ float s_c[TILE_B][152];               // own 150 c values
    __shared__ float s_gbuf[TILE_B][ROWS];           // own gate preacts
    __shared__ float s_emp[TILE_B][kT][10];          // emission partial chunks
    __shared__ float s_emf[40], s_emf2[40];          // reduced partials (q0)
    // total LDS ~153 KB -> 1 block/CU.
    float (*hhp)[4][ROWS] = (float(*)[4][ROWS])&s_Ax[0][0];  // [4][4][600] = 38.4 KB

    const int bi   = blockIdx.x;
    const int xcd  = bi & 7;
    const int dir  = xcd >> 2;
    const int q    = (xcd >> 1) & 1;
    const int tile = (bi >> 3) * 2 + (xcd & 1);      // 0..63
    const int tid  = threadIdx.x;
    const int wv   = tid >> 6, lane = tid & 63;

    const float4* wih4 = wt + ((size_t)(dir * 2 + 0)) * 2 * SLICE_F4 + (size_t)q * SLICE_F4;
    const float4* whh4 = wt + ((size_t)(dir * 2 + 1)) * 2 * SLICE_F4 + (size_t)q * SLICE_F4;
    const float*  bih  = dir ? bih_b : bih_f;
    const float*  bhh  = dir ? bhh_b : bhh_f;
    float* emout = em_all + (size_t)dir * EMSZ;

    const int gid2 = (dir * 64 + tile) * 2;
    float* hx_own  = hxh + (size_t)(gid2 + q)       * 2 * ROWS;
    float* hx_par  = hxh + (size_t)(gid2 + (1 - q)) * 2 * ROWS;
    float* hxa_own = hxa + (size_t)(gid2 + q)       * 2 * 40;
    float* hxa_par = hxa + (size_t)(gid2 + (1 - q)) * 2 * 40;
    int* flag_own  = flags + gid2 + q;
    int* flag_par  = flags + gid2 + (1 - q);

    // IH geometry: slice sl = (wave>=5), row-block wb, rows r0/r1 = wb*128+lane(+64)
    const int ih_sl = (wv >= 5) ? 1 : 0;
    const int ih_wb = ih_sl ? (wv - 5) : wv;
    const int ih_r0 = ih_wb * 128 + lane;
    const int ih_r1 = ih_r0 + 64;
    float bs0 = 0.f, bs1 = 0.f;
    if (ih_sl == 0) {
        if (ih_r0 < ROWS) bs0 = bias_of(ih_r0, q, bih, bhh);
        if (ih_r1 < ROWS) bs1 = bias_of(ih_r1, q, bih, bhh);
    }

    for (int i = tid; i < TILE_B * 304; i += NTH) (&s_h[0][0])[i] = 0.0f;
    for (int i = tid; i < TILE_B * 152; i += NTH) (&s_c[0][0])[i] = 0.0f;
    for (int i = tid; i < 32 * 304;     i += NTH) (&s_Ax[0][0])[i] = 0.0f;  // pad cols 0
    __syncthreads();

    for (int tc = 0; tc < kS / TCHUNK; ++tc) {
        // ---- embedding gather: 32 (tt,b2) rows, 20 lanes each ------------------
        {
            const int rr = tid / 20, ln = tid - rr * 20;
            const int tt = rr >> 2, b2 = rr & 3;
            const int t  = tc * TCHUNK + tt;
            const int s  = dir ? (kS - 1 - t) : t;
            const int token = x[(tile * TILE_B + b2) * kS + s];
            const float* erow = emb + (size_t)token * kE;
            for (int e = ln; e < kE; e += 20) s_Ax[rr][e] = erow[e];
        }
        __syncthreads();

        // ---- input projection: k-split, 4 passes of 8 columns ------------------
        // wave -> (slice of 38 kc, 128-row block); 2 load streams + prefetch.
        for (int pass = 0; pass < 4; ++pass) {
            const int ub = pass * 8;
            {
                const int kc0 = ih_sl * 38;
                float acc0[8], acc1[8];
#pragma unroll
                for (int u = 0; u < 8; ++u) { acc0[u] = bs0; acc1[u] = bs1; }
                const float4* wl = wih4 + (size_t)kc0 * RRP + ih_wb * 128 + lane;
                float4 c0 = wl[0], c1 = wl[64]; wl += RRP;
#pragma unroll 1
                for (int kc = 0; kc < 38; ++kc) {
                    const float4 n0 = wl[0], n1 = wl[64]; wl += RRP;
                    const int k4 = (kc0 + kc) * 4;
#pragma unroll
                    for (int u = 0; u < 8; ++u) {
                        const float4 a = *(const float4*)&s_Ax[ub + u][k4];
                        FMA4(c0, a, acc0[u]);
                        FMA4(c1, a, acc1[u]);
                    }
                    c0 = n0; c1 = n1;
                }
                if (ih_sl == 0) {
                    if (ih_r0 < ROWS) {
#pragma unroll
                        for (int u = 0; u < 8; ++u) s_pre[(ub + u) * ROWS + ih_r0] = acc0[u];
                    }
                    if (ih_r1 < ROWS) {
#pragma unroll
                        for (int u = 0; u < 8; ++u) s_pre[(ub + u) * ROWS + ih_r1] = acc1[u];
                    }
                } else {
                    if (ih_r0 < ROWS) {
#pragma unroll
                        for (int u = 0; u < 8; ++u) s_ihp[u][ih_r0] = acc0[u];
                    }
                    if (ih_r1 < ROWS) {
#pragma unroll
                        for (int u = 0; u < 8; ++u) s_ihp[u][ih_r1] = acc1[u];
                    }
                }
            }
            __syncthreads();
            if (tid < ROWS) {
#pragma unroll
                for (int u = 0; u < 8; ++u)
                    s_pre[(ub + u) * ROWS + tid] += s_ihp[u][tid];
            }
            __syncthreads();
        }

        // ---- recurrent steps ---------------------------------------------------
        for (int tt = 0; tt < TCHUNK; ++tt) {
            const int t   = tc * TCHUNK + tt;
            const int s   = dir ? (kS - 1 - t) : t;
            const int par = t & 1;

            // HH k-split partials: 8 waves = (slice s4 of 19 kc, batch-pair bp);
            // 10 row-group streams per wave, 5-wide rolling window.
            if (tid < 512) {
                const int s4 = wv >> 1, bp = wv & 1;
                const int kc0 = s4 * 19;
                float aA[10], aB[10];
#pragma unroll
                for (int rg = 0; rg < 10; ++rg) { aA[rg] = 0.f; aB[rg] = 0.f; }
                const float4* wb_ = whh4 + (size_t)kc0 * RRP + lane;
                float4 lo[5];
#pragma unroll
                for (int g = 0; g < 5; ++g) lo[g] = wb_[g * 64];
#pragma unroll 1
                for (int kc = 0; kc < 19; ++kc) {
                    const float4* wk = wb_ + (size_t)kc * RRP;
                    float4 hi[5];
#pragma unroll
                    for (int g = 0; g < 5; ++g) hi[g] = wk[(5 + g) * 64];
                    const int k4 = (kc0 + kc) * 4;
                    const float4 h0 = *(const float4*)&s_h[2 * bp + 0][k4];
                    const float4 h1 = *(const float4*)&s_h[2 * bp + 1][k4];
#pragma unroll
                    for (int g = 0; g < 5; ++g) {
                        FMA4(lo[g], h0, aA[g]);
                        FMA4(lo[g], h1, aB[g]);
                    }
#pragma unroll
                    for (int g = 0; g < 5; ++g) lo[g] = wk[RRP + g * 64];  // next kc rg0-4
#pragma unroll
                    for (int g = 0; g < 5; ++g) {
                        FMA4(hi[g], h0, aA[5 + g]);
                        FMA4(hi[g], h1, aB[5 + g]);
                    }
                }
#pragma unroll
                for (int rg = 0; rg < 10; ++rg) {
                    const int row = rg * 64 + lane;
                    if (row < ROWS) {
                        hhp[s4][2 * bp + 0][row] = aA[rg];
                        hhp[s4][2 * bp + 1][row] = aB[rg];
                    }
                }
            }
            __syncthreads();

            // reduce partials + pre -> gate preacts
            if (tid < ROWS) {
#pragma unroll
                for (int b = 0; b < TILE_B; ++b) {
                    float g = s_pre[(tt * 4 + b) * ROWS + tid];
#pragma unroll
                    for (int s4 = 0; s4 < 4; ++s4) g += hhp[s4][b][tid];
                    s_gbuf[b][tid] = g;
                }
            }
            __syncthreads();

            // cell update for own 150 units x 4 batches; store h to exchange buf
            if (tid < ROWS) {
                const int b = tid / 150, i2 = tid - b * 150;
                const float gi = s_gbuf[b][i2];
                const float gf = s_gbuf[b][150 + i2];
                const float gg = s_gbuf[b][300 + i2];
                const float go = s_gbuf[b][450 + i2];
                const float c  = sigmoidf_(gf) * s_c[b][i2] + sigmoidf_(gi) * tanhf(gg);
                const float h  = sigmoidf_(go) * tanhf(c);
                s_c[b][i2] = c;
                s_h[b][q * 150 + i2] = h;
                __hip_atomic_store(&hx_own[par * ROWS + tid], h,
                                   __ATOMIC_RELAXED, __HIP_MEMORY_SCOPE_AGENT);
            }
            __syncthreads();

            // emission partials over own slice
            if (tid < 360) {
                const int b = tid / 90, rem = tid - b * 90;
                const int tag = rem / 10, ch = rem - tag * 10;
                const int n0 = ch * 15;
                const float* wrow = w_proj + tag * (2 * kH) + dir * kH + q * 150 + n0;
                const float* hrow = &s_h[b][q * 150 + n0];
                float sum = 0.0f;
#pragma unroll
                for (int k2 = 0; k2 < 15; ++k2) sum += hrow[k2] * wrow[k2];
                s_emp[b][tag][ch] = sum;
            }
            __syncthreads();
            if (tid < 36) {
                const int b = tid / 9, tag = tid - b * 9;
                float v = 0.0f;
#pragma unroll
                for (int ch = 0; ch < 10; ++ch) v += s_emp[b][tag][ch];
                if (q) __hip_atomic_store(&hxa_own[par * 40 + tid], v,
                                          __ATOMIC_RELAXED, __HIP_MEMORY_SCOPE_AGENT);
                else   s_emf[tid] = v;
            }
            // each wave drains its own agent stores, barrier, then signal
            asm volatile("s_waitcnt vmcnt(0)" ::: "memory");
            __syncthreads();
            if (tid == 0) {
                __hip_atomic_store(flag_own, t + 1,
                                   __ATOMIC_RELAXED, __HIP_MEMORY_SCOPE_AGENT);
                int spins = 0;
                while (__hip_atomic_load(flag_par, __ATOMIC_RELAXED,
                                         __HIP_MEMORY_SCOPE_AGENT) < t + 1) {
                    __builtin_amdgcn_s_sleep(2);
                    if (++spins > (1 << 22)) break;   // hang safety
                }
            }
            __syncthreads();
            // pull partner's h half (+ partner emission partial for q0)
            if (tid < ROWS) {
                const int b = tid / 150, i2 = tid - b * 150;
                s_h[b][(1 - q) * 150 + i2] =
                    __hip_atomic_load(&hx_par[par * ROWS + tid],
                                      __ATOMIC_RELAXED, __HIP_MEMORY_SCOPE_AGENT);
            } else if (!q && tid < ROWS + 36) {
                s_emf2[tid - ROWS] =
                    __hip_atomic_load(&hxa_par[par * 40 + (tid - ROWS)],
                                      __ATOMIC_RELAXED, __HIP_MEMORY_SCOPE_AGENT);
            }
            __syncthreads();
            if (!q && tid < 36) {
                const int b = tid / 9, tag = tid - b * 9;
                emout[((size_t)s * kB + tile * TILE_B + b) * kT + tag] =
                    s_emf[tid] + s_emf2[tid];
            }
            // next phase writes hhp/s_pre regions, separated by >=2 barriers
        }
    }
}

// -----------------------------------------------------------------------------
// CRF Viterbi decode (unchanged). 9 lanes per batch row.
// -----------------------------------------------------------------------------
__global__ __launch_bounds__(256) void ner_viterbi_kernel(
    const float* __restrict__ em_all,
    const float* __restrict__ b_proj,
    const float* __restrict__ start_t,
    const float* __restrict__ end_t,
    const float* __restrict__ trans,
    int*         __restrict__ out)
{
    const float* em_f = em_all;
    const float* em_b = em_all + EMSZ;

    __shared__ uint8_t bp[kS - 1][28][kT];

    const int tid  = threadIdx.x;
    const int wave = tid >> 6;
    const int lane = tid & 63;
    const int g    = lane / kT;
    const int nx   = lane % kT;
    const bool active = (g < 7);
    const int gg   = wave * 7 + g;
    const int b    = blockIdx.x * 28 + (active ? gg : 0);
    const bool valid = active && (b < kB);
    const int beff = (b < kB) ? b : (kB - 1);
    const int base = g * kT;

    float tcol[kT];
#pragma unroll
    for (int p = 0; p < kT; ++p) tcol[p] = trans[p * kT + nx];
    const float bpj = b_proj[nx];

    float score = start_t[nx]
                + em_f[(size_t)beff * kT + nx]
                + em_b[(size_t)beff * kT + nx]
                + bpj;

    for (int t = 1; t < kS; ++t) {
        const size_t ei = ((size_t)t * kB + beff) * kT + nx;
        const float em = em_f[ei] + em_b[ei] + bpj;
        float best = -3.402823466e38f;
        int bidx = 0;
#pragma unroll
        for (int p = 0; p < kT; ++p) {
            const float sp = __shfl(score, base + p, 64);
            const float cand = sp + tcol[p];
            if (cand > best) { best = cand; bidx = p; }
        }
        if (valid) bp[t - 1][gg][nx] = (uint8_t)bidx;
        score = best + em;
    }

    score += end_t[nx];
    float best = -3.402823466e38f;
    int last = 0;
#pragma unroll
    for (int p = 0; p < kT; ++p) {
        const float sp = __shfl(score, base + p, 64);
        if (sp > best) { best = sp; last = p; }
    }

    __syncthreads();

    if (valid && nx == 0) {
        int cur = last;
        out[beff * kS + (kS - 1)] = cur;
        for (int t = kS - 2; t >= 0; --t) {
            cur = bp[t][gg][cur];
            out[beff * kS + t] = cur;
        }
    }
}

// -----------------------------------------------------------------------------
extern "C" void kernel_launch(void* const* d_in, const int* in_sizes, int n_in,
                              void* d_out, int out_size, void* d_ws, size_t ws_size,
                              hipStream_t stream) {
    const int*   x       = (const int*)  d_in[0];
    const float* emb     = (const float*)d_in[1];
    const float* w_ih_f  = (const float*)d_in[2];
    const float* w_hh_f  = (const float*)d_in[3];
    const float* b_ih_f  = (const float*)d_in[4];
    const float* b_hh_f  = (const float*)d_in[5];
    const float* w_ih_b  = (const float*)d_in[6];
    const float* w_hh_b  = (const float*)d_in[7];
    const float* b_ih_b  = (const float*)d_in[8];
    const float* b_hh_b  = (const float*)d_in[9];
    const float* w_proj  = (const float*)d_in[10];
    const float* b_proj  = (const float*)d_in[11];
    const float* start_t = (const float*)d_in[12];
    const float* end_t   = (const float*)d_in[13];
    const float* trans   = (const float*)d_in[14];

    // workspace: em (4.72 MB) | wt 4x2 padded slices (6.31 MB) | hxh (1.23 MB) |
    //            hxa (82 KB) | flags (1 KB)  => ~12.4 MB
    float*  em_all = (float*)d_ws;
    float4* wt     = (float4*)((char*)d_ws + (size_t)2 * EMSZ * 4);
    float*  hxh    = (float*)((char*)wt + (size_t)4 * 2 * SLICE_F4 * sizeof(float4));
    float*  hxa    = hxh + (size_t)256 * 2 * ROWS;
    int*    flags  = (int*)(hxa + (size_t)256 * 2 * 40);

    dim3 tgrid((2 * SLICE_F4 + 255) / 256, 4);
    transpose_w_all<<<tgrid, 256, 0, stream>>>(w_ih_f, w_hh_f, w_ih_b, w_hh_b, wt, flags);

    // 256 blocks (2 dirs x 2 q x 64 tiles); 76.8 KB dynamic LDS (s_pre)
    ner_bilstm_kernel<<<256, NTH, 32 * ROWS * sizeof(float), stream>>>(
        x, emb, wt, b_ih_f, b_hh_f, b_ih_b, b_hh_b, w_proj,
        em_all, hxh, hxa, flags);

    ner_viterbi_kernel<<<10, 256, 0, stream>>>(
        em_all, b_proj, start_t, end_t, trans, (int*)d_out);
}